// Round 4
// baseline (194.002 us; speedup 1.0000x reference)
//
#include <hip/hip_runtime.h>
#include <math.h>

#define BB 4
#define LQ 2048
#define LK 2048
#define HD 8
#define VD 64
#define HV 512
#define SP 72   // padded LDS row stride (bf16 elems) for cvt/proj kernels

typedef __attribute__((ext_vector_type(8))) short bf16x8;
typedef __attribute__((ext_vector_type(4))) float f32x4;

static __device__ __forceinline__ unsigned short f2bf(float f) {  // RNE
    unsigned u = __builtin_bit_cast(unsigned, f);
    unsigned r = (u + 0x7fffu + ((u >> 16) & 1u)) >> 16;
    return (unsigned short)r;
}

static __device__ __forceinline__ float fast_exp2(float x) {
#if __has_builtin(__builtin_amdgcn_exp2f)
    return __builtin_amdgcn_exp2f(x);
#else
    return __expf(x * 0.69314718f);
#endif
}

// pack hi16(even), hi16(odd) -> one dword (bf16 truncation x2, 1 VALU op)
static __device__ __forceinline__ unsigned pack_trunc(float even, float odd) {
    return __builtin_amdgcn_perm(__builtin_bit_cast(unsigned, odd),
                                 __builtin_bit_cast(unsigned, even), 0x07060302u);
}

// ---------------- values fp32 [b][k][h][v] -> bf16 [b][h][v][k] ----------------
__global__ __launch_bounds__(256) void cvt_vals(
    const float* __restrict__ vals, unsigned short* __restrict__ vals_t)
{
    __shared__ unsigned short st[64 * SP];   // [v][k] tile
    const int tid = threadIdx.x;
    const int kt = blockIdx.x, h = blockIdx.y, b = blockIdx.z;

    const int k  = tid >> 2;
    const int vb = (tid & 3) * 16;
    const float* src = vals + (((size_t)(b * LK + kt * 64 + k) * HD + h)) * VD + vb;
    float4 f0 = *(const float4*)(src);
    float4 f1 = *(const float4*)(src + 4);
    float4 f2 = *(const float4*)(src + 8);
    float4 f3 = *(const float4*)(src + 12);
    const float fv[16] = {f0.x,f0.y,f0.z,f0.w, f1.x,f1.y,f1.z,f1.w,
                          f2.x,f2.y,f2.z,f2.w, f3.x,f3.y,f3.z,f3.w};
#pragma unroll
    for (int j = 0; j < 16; ++j) st[(vb + j) * SP + k] = f2bf(fv[j]);
    __syncthreads();

    const int v  = tid >> 2;
    const int kb = (tid & 3) * 16;
    uint4 o0 = *(const uint4*)&st[v * SP + kb];
    uint4 o1 = *(const uint4*)&st[v * SP + kb + 8];
    unsigned short* dst = vals_t + ((size_t)((b * HD + h) * VD + v)) * LK + kt * 64 + kb;
    *(uint4*)dst       = o0;
    *(uint4*)(dst + 8) = o1;
}

// ---------------- W fp32 [512][512] -> bf16 ----------------
__global__ __launch_bounds__(256) void cvt_w(
    const float* __restrict__ w, unsigned short* __restrict__ wb)
{
    const int i = (blockIdx.x * 256 + threadIdx.x) * 4;
    float4 f = *(const float4*)(w + i);
    ushort4 o;
    o.x = f2bf(f.x); o.y = f2bf(f.y); o.z = f2bf(f.z); o.w = f2bf(f.w);
    *(ushort4*)(wb + i) = o;
}

// ---------------- fused gaussian attention: zero LDS, zero barriers ----------------
// grid 512 blocks, 256 thr. Decode: xcd=bi&7, sub=(bi>>3)&3, qc=bi>>5.
// slice = xcd*4+sub -> (b,h); blocks sharing a slice land on one XCD (L2 locality).
// wave handles 32 q (2 strips of 16) x one head; everything from global/registers.
__global__ __launch_bounds__(256) void attend4(
    const float* __restrict__ qpos,
    const float* __restrict__ kpos,
    const unsigned short* __restrict__ vals_t,
    const int*   __restrict__ kmask,
    const float* __restrict__ ls,
    unsigned short* __restrict__ attended)
{
    const int tid = threadIdx.x;
    const int bi  = blockIdx.x;
    const int xcd = bi & 7, sub = (bi >> 3) & 3, qc = bi >> 5;
    const int slice = xcd * 4 + sub;
    const int b = slice >> 3, h = slice & 7;
    const int wave = tid >> 6, lane = tid & 63;
    const int ln = lane & 15, kq = lane >> 4;

    const float lsh = ls[h];
    const float ch  = -1.44269504f / (lsh * lsh);   // exp(-d2/ls^2) = exp2(ch*d2)

    const int qbase = qc * 128 + wave * 32;
    float qx[2], qy[2], qz[2];
#pragma unroll
    for (int st = 0; st < 2; ++st) {
        const float* qp = qpos + (size_t)(b * LQ + qbase + st * 16 + ln) * 3;
        qx[st] = qp[0]; qy[st] = qp[1]; qz[st] = qp[2];
    }

    const unsigned short* vbase = vals_t + (size_t)((b * HD + h) * VD) * LK;
    const float* kpb = kpos + (size_t)b * LK * 3;
    const int*   kmb = kmask + b * LK;

    f32x4 acc[2][4];
#pragma unroll
    for (int i = 0; i < 2; ++i)
#pragma unroll
        for (int j = 0; j < 4; ++j) acc[i][j] = (f32x4){0.f, 0.f, 0.f, 0.f};
    float pden[2] = {0.f, 0.f};

    for (int t = 0; t < 32; ++t) {
        // ---- B-fragments straight from global (L2-resident slice) ----
        bf16x8 bf0[4], bf1[4];
#pragma unroll
        for (int vt = 0; vt < 4; ++vt) {
            const unsigned short* bp = vbase + (size_t)(vt * 16 + ln) * LK + t * 64 + kq * 8;
            bf0[vt] = *(const bf16x8*)(bp);
            bf1[vt] = *(const bf16x8*)(bp + 32);
        }

        // ---- scores, one 8-k octet half at a time (A-frag layout in regs) ----
        bf16x8 afr[2][2];
#pragma unroll
        for (int half = 0; half < 2; ++half) {
            const int K0 = t * 64 + half * 32 + kq * 8;
            float4 kc[6];
            const float* ksrc = kpb + (size_t)K0 * 3;   // 24 contiguous floats
#pragma unroll
            for (int j = 0; j < 6; ++j) kc[j] = ((const float4*)ksrc)[j];
            int mk[8];
            *(int4*)&mk[0] = *(const int4*)(kmb + K0);
            *(int4*)&mk[4] = *(const int4*)(kmb + K0 + 4);
            const float* kcf = (const float*)kc;
            float xs[8], ys[8], zs[8];
#pragma unroll
            for (int j = 0; j < 8; ++j) {
                xs[j] = mk[j] ? 3.0e37f : kcf[3 * j];   // masked -> d2 huge -> exp2 -> 0
                ys[j] = kcf[3 * j + 1];
                zs[j] = kcf[3 * j + 2];
            }
#pragma unroll
            for (int st = 0; st < 2; ++st) {
                float s[8];
#pragma unroll
                for (int j = 0; j < 8; ++j) {
                    const float dx = qx[st] - xs[j];
                    const float dy = qy[st] - ys[j];
                    const float dz = qz[st] - zs[j];
                    const float d2 = fmaf(dx, dx, fmaf(dy, dy, dz * dz));
                    const float sc = fast_exp2(d2 * ch);
                    pden[st] += sc;
                    s[j] = sc;
                }
                unsigned pk[4];
#pragma unroll
                for (int p = 0; p < 4; ++p) pk[p] = pack_trunc(s[2 * p], s[2 * p + 1]);
                afr[st][half] = __builtin_bit_cast(bf16x8, *(uint4*)pk);
            }
        }

        // ---- MFMA ----
#pragma unroll
        for (int st = 0; st < 2; ++st)
#pragma unroll
            for (int vt = 0; vt < 4; ++vt) {
                acc[st][vt] = __builtin_amdgcn_mfma_f32_16x16x32_bf16(afr[st][0], bf0[vt], acc[st][vt], 0, 0, 0);
                acc[st][vt] = __builtin_amdgcn_mfma_f32_16x16x32_bf16(afr[st][1], bf1[vt], acc[st][vt], 0, 0, 0);
            }
    }

    // ---- denominator: reduce over kq groups, redistribute to C-layout rows ----
    float inv[2];
#pragma unroll
    for (int st = 0; st < 2; ++st) {
        float v = pden[st];
        v += __shfl_xor(v, 16, 64);
        v += __shfl_xor(v, 32, 64);
        inv[st] = 1.0f / (v + 1e-5f);          // valid for q = st*16 + ln
    }
    float ivq[2][4];
#pragma unroll
    for (int st = 0; st < 2; ++st)
#pragma unroll
        for (int r = 0; r < 4; ++r) ivq[st][r] = __shfl(inv[st], kq * 4 + r, 64);

#pragma unroll
    for (int st = 0; st < 2; ++st)
#pragma unroll
        for (int vt = 0; vt < 4; ++vt)
#pragma unroll
            for (int r = 0; r < 4; ++r) {
                const int q = qbase + st * 16 + kq * 4 + r;
                attended[(size_t)(b * LQ + q) * HV + h * VD + vt * 16 + ln] =
                    f2bf(acc[st][vt][r] * ivq[st][r]);
            }
}

// ---------------- projection: C[8192][512] = A_bf16 @ Wb^T, 128x128 tiles ----------------
__global__ __launch_bounds__(256, 1) void proj4(
    const unsigned short* __restrict__ A,
    const unsigned short* __restrict__ Wb,
    float* __restrict__ C)
{
    __shared__ __align__(16) unsigned short sA[128 * SP];
    __shared__ __align__(16) unsigned short sW[128 * SP];

    const int tid = threadIdx.x;
    const int n0 = blockIdx.x * 128, m0 = blockIdx.y * 128;
    const int wave = tid >> 6, lane = tid & 63;
    const int ln = lane & 15, kq = lane >> 4;
    const int mw = (wave >> 1) * 64, nw = (wave & 1) * 64;
    const int sr = tid >> 1, sh = (tid & 1) * 32;

    f32x4 acc[4][4];
#pragma unroll
    for (int i = 0; i < 4; ++i)
#pragma unroll
        for (int j = 0; j < 4; ++j) acc[i][j] = (f32x4){0.f, 0.f, 0.f, 0.f};

    for (int k0 = 0; k0 < 512; k0 += 64) {
        __syncthreads();
        {
            const unsigned short* a = A  + (size_t)(m0 + sr) * 512 + k0 + sh;
            const unsigned short* w = Wb + (size_t)(n0 + sr) * 512 + k0 + sh;
            uint4 a0 = ((const uint4*)a)[0], a1 = ((const uint4*)a)[1],
                  a2 = ((const uint4*)a)[2], a3 = ((const uint4*)a)[3];
            uint4 w0 = ((const uint4*)w)[0], w1 = ((const uint4*)w)[1],
                  w2 = ((const uint4*)w)[2], w3 = ((const uint4*)w)[3];
            unsigned short* da = &sA[sr * SP + sh];
            unsigned short* dw = &sW[sr * SP + sh];
            ((uint4*)da)[0] = a0; ((uint4*)da)[1] = a1;
            *(uint4*)(da + 16) = a2; *(uint4*)(da + 24) = a3;
            ((uint4*)dw)[0] = w0; ((uint4*)dw)[1] = w1;
            *(uint4*)(dw + 16) = w2; *(uint4*)(dw + 24) = w3;
        }
        __syncthreads();

        bf16x8 af[4][2], bfr[4][2];
#pragma unroll
        for (int mt = 0; mt < 4; ++mt) {
            const unsigned short* ap = &sA[(mw + mt * 16 + ln) * SP + kq * 8];
            af[mt][0] = *(const bf16x8*)(ap);
            af[mt][1] = *(const bf16x8*)(ap + 32);
        }
#pragma unroll
        for (int nt = 0; nt < 4; ++nt) {
            const unsigned short* bp = &sW[(nw + nt * 16 + ln) * SP + kq * 8];
            bfr[nt][0] = *(const bf16x8*)(bp);
            bfr[nt][1] = *(const bf16x8*)(bp + 32);
        }
#pragma unroll
        for (int mt = 0; mt < 4; ++mt)
#pragma unroll
            for (int nt = 0; nt < 4; ++nt) {
                acc[mt][nt] = __builtin_amdgcn_mfma_f32_16x16x32_bf16(af[mt][0], bfr[nt][0], acc[mt][nt], 0, 0, 0);
                acc[mt][nt] = __builtin_amdgcn_mfma_f32_16x16x32_bf16(af[mt][1], bfr[nt][1], acc[mt][nt], 0, 0, 0);
            }
    }

#pragma unroll
    for (int mt = 0; mt < 4; ++mt)
#pragma unroll
        for (int nt = 0; nt < 4; ++nt)
#pragma unroll
            for (int r = 0; r < 4; ++r)
                C[(size_t)(m0 + mw + mt * 16 + kq * 4 + r) * 512 + n0 + nw + nt * 16 + ln] =
                    acc[mt][nt][r];
}

extern "C" void kernel_launch(void* const* d_in, const int* in_sizes, int n_in,
                              void* d_out, int out_size, void* d_ws, size_t ws_size,
                              hipStream_t stream) {
    const float* qpos  = (const float*)d_in[0];
    const float* kpos  = (const float*)d_in[1];
    const float* vals  = (const float*)d_in[2];
    const int*   kmask = (const int*)  d_in[3];
    const float* ls    = (const float*)d_in[4];
    const float* wout  = (const float*)d_in[5];
    float* out = (float*)d_out;

    unsigned short* vals_t   = (unsigned short*)d_ws;                    // 8 MiB
    unsigned short* attended = vals_t + (size_t)4 * 1024 * 1024;         // 8 MiB
    unsigned short* w_bf     = vals_t + (size_t)8 * 1024 * 1024;         // 512 KiB

    cvt_vals<<<dim3(32, HD, BB), 256, 0, stream>>>(vals, vals_t);
    cvt_w   <<<dim3(256), 256, 0, stream>>>(wout, w_bf);
    attend4 <<<dim3(512), 256, 0, stream>>>(qpos, kpos, vals_t, kmask, ls, attended);
    proj4   <<<dim3(4, 64), 256, 0, stream>>>(attended, w_bf, out);
}